// Round 1
// baseline (8095.259 us; speedup 1.0000x reference)
//
#include <hip/hip_runtime.h>
#include <hip/hip_bf16.h>
#include <stdint.h>

#define F_DIM 12288
#define D_DIM 768
#define M_DIM 4096   // B*S tokens
#define K_TOP 64
#define COL_CAP 256

// ------------------------------------------------------------------
// Mask dtype detection: 0 = int32, 1 = uint8/bool, 2 = float32
// ------------------------------------------------------------------
__global__ void detect_mask_kernel(const void* mask, int* mode) {
  __shared__ int weird, misal;
  if (threadIdx.x == 0) { weird = 0; misal = 0; }
  __syncthreads();
  const unsigned char* p = (const unsigned char*)mask;
  for (int i = threadIdx.x; i < (1 << 20); i += blockDim.x) {
    unsigned char b = p[i];
    if (b != 0) {
      if (b != 1) atomicOr(&weird, 1);          // float32 bytes (0x80 / 0x3F)
      else if (i & 3) atomicOr(&misal, 1);      // 1-byte bools off word boundary
    }
  }
  __syncthreads();
  if (threadIdx.x == 0) mode[0] = weird ? 2 : (misal ? 1 : 0);
}

// ------------------------------------------------------------------
// Single-pass CSR build by column (up-feature). Fixed capacity 256/col
// (mean 122.9, sd 11 -> 256 is +12 sigma, never overflows).
// ------------------------------------------------------------------
__global__ void count_fill_kernel(const void* mask, const int* mode_p,
                                  int* col_cnt, unsigned short* rows) {
  const int mode = *mode_p;
  const int total = F_DIM * F_DIM;  // 150,994,944 < 2^31
  for (int e = blockIdx.x * blockDim.x + threadIdx.x; e < total;
       e += gridDim.x * blockDim.x) {
    bool set;
    if (mode == 0)      set = ((const int*)mask)[e] != 0;
    else if (mode == 1) set = ((const unsigned char*)mask)[e] != 0;
    else                set = ((const float*)mask)[e] != 0.0f;
    if (set) {
      int j = e % F_DIM;          // up feature (column)
      int i = e / F_DIM;          // down feature (row)
      int pos = atomicAdd(&col_cnt[j], 1);
      if (pos < COL_CAP) rows[j * COL_CAP + pos] = (unsigned short)i;
    }
  }
}

// ------------------------------------------------------------------
// Masked virtual values: V[i,j] = dot(W_enc_down[i,:], W_dec_up[:,j])
// One wave per column j; Wu column held in registers (12/lane).
// ------------------------------------------------------------------
__global__ __launch_bounds__(256) void csr_vals_kernel(
    const float* __restrict__ Wdu /*[768][12288]*/,
    const float* __restrict__ Wed /*[12288][768]*/,
    const unsigned short* __restrict__ rows, const int* __restrict__ col_cnt,
    float* __restrict__ vals) {
  const int j = blockIdx.x * 4 + (threadIdx.x >> 6);
  const int lane = threadIdx.x & 63;
  float wu[12];
#pragma unroll
  for (int c = 0; c < 12; ++c)
    wu[c] = Wdu[(size_t)(lane + 64 * c) * F_DIM + j];
  const int cnt = min(col_cnt[j], COL_CAP);
  for (int n = 0; n < cnt; ++n) {
    int i = rows[j * COL_CAP + n];
    const float* wr = Wed + (size_t)i * D_DIM;
    float s = 0.0f;
#pragma unroll
    for (int c = 0; c < 12; ++c) s = fmaf(wu[c], wr[lane + 64 * c], s);
    for (int off = 32; off; off >>= 1) s += __shfl_xor(s, off);
    if (lane == 0) vals[j * COL_CAP + n] = s;
  }
}

// ------------------------------------------------------------------
// bias_contrib[f] = dot(b_dec_up, W_enc_down[f,:])  (fp64 acc)
// ------------------------------------------------------------------
__global__ __launch_bounds__(256) void bias_contrib_kernel(
    const float* __restrict__ bdu, const float* __restrict__ Wed,
    float* __restrict__ out) {
  const int f = blockIdx.x * 4 + (threadIdx.x >> 6);
  const int lane = threadIdx.x & 63;
  double s = 0.0;
#pragma unroll
  for (int c = 0; c < 12; ++c) {
    int d = lane + 64 * c;
    s += (double)bdu[d] * (double)Wed[(size_t)f * D_DIM + d];
  }
  for (int off = 32; off; off >>= 1) s += __shfl_xor(s, off);
  if (lane == 0) out[f] = (float)s;
}

// ------------------------------------------------------------------
// GEMM, fp32 in / fp64 accumulate.  C[m,n] = post( sum_k (A[m,k]-bsub[k])*B[n,k] )
// tile 64x64, K-step 32, 256 threads, 4x4 per thread.
// LDS layout [k][m]: inner-loop reads are broadcast (A) / 2-way (B) = free.
// ------------------------------------------------------------------
template <int SUBB, int RELU, int ADD1, int ADD2>
__global__ __launch_bounds__(256) void gemm_f64(
    const float* __restrict__ A, const float* __restrict__ Bm,
    float* __restrict__ C, const float* __restrict__ bsub,
    const float* __restrict__ a1v, const float* __restrict__ a2v,
    int M, int N, int K) {
  __shared__ float As[32][64];
  __shared__ float Bs[32][64];
  const int tx = threadIdx.x & 15, ty = threadIdx.x >> 4;
  const int m0 = blockIdx.y << 6, n0 = blockIdx.x << 6;
  const int r = threadIdx.x & 63;
  const int kc = (threadIdx.x >> 6) << 3;  // 0,8,16,24
  double acc[4][4];
#pragma unroll
  for (int i = 0; i < 4; ++i)
#pragma unroll
    for (int j = 0; j < 4; ++j) acc[i][j] = 0.0;
  const float* Arow = A + (size_t)(m0 + r) * K + kc;
  const float* Brow = Bm + (size_t)(n0 + r) * K + kc;
  for (int k0 = 0; k0 < K; k0 += 32) {
    float4 x0 = *(const float4*)(Arow + k0);
    float4 x1 = *(const float4*)(Arow + k0 + 4);
    if (SUBB) {
      const float* bp = bsub + k0 + kc;
      x0.x -= bp[0]; x0.y -= bp[1]; x0.z -= bp[2]; x0.w -= bp[3];
      x1.x -= bp[4]; x1.y -= bp[5]; x1.z -= bp[6]; x1.w -= bp[7];
    }
    float4 y0 = *(const float4*)(Brow + k0);
    float4 y1 = *(const float4*)(Brow + k0 + 4);
    As[kc + 0][r] = x0.x; As[kc + 1][r] = x0.y; As[kc + 2][r] = x0.z; As[kc + 3][r] = x0.w;
    As[kc + 4][r] = x1.x; As[kc + 5][r] = x1.y; As[kc + 6][r] = x1.z; As[kc + 7][r] = x1.w;
    Bs[kc + 0][r] = y0.x; Bs[kc + 1][r] = y0.y; Bs[kc + 2][r] = y0.z; Bs[kc + 3][r] = y0.w;
    Bs[kc + 4][r] = y1.x; Bs[kc + 5][r] = y1.y; Bs[kc + 6][r] = y1.z; Bs[kc + 7][r] = y1.w;
    __syncthreads();
#pragma unroll
    for (int k = 0; k < 32; ++k) {
      const float4 av = *(const float4*)(&As[k][ty << 2]);
      const float4 bv = *(const float4*)(&Bs[k][tx << 2]);
      const double a0 = av.x, a1 = av.y, a2 = av.z, a3 = av.w;
      const double b0 = bv.x, b1 = bv.y, b2 = bv.z, b3 = bv.w;
      acc[0][0] = fma(a0, b0, acc[0][0]); acc[0][1] = fma(a0, b1, acc[0][1]);
      acc[0][2] = fma(a0, b2, acc[0][2]); acc[0][3] = fma(a0, b3, acc[0][3]);
      acc[1][0] = fma(a1, b0, acc[1][0]); acc[1][1] = fma(a1, b1, acc[1][1]);
      acc[1][2] = fma(a1, b2, acc[1][2]); acc[1][3] = fma(a1, b3, acc[1][3]);
      acc[2][0] = fma(a2, b0, acc[2][0]); acc[2][1] = fma(a2, b1, acc[2][1]);
      acc[2][2] = fma(a2, b2, acc[2][2]); acc[2][3] = fma(a2, b3, acc[2][3]);
      acc[3][0] = fma(a3, b0, acc[3][0]); acc[3][1] = fma(a3, b1, acc[3][1]);
      acc[3][2] = fma(a3, b2, acc[3][2]); acc[3][3] = fma(a3, b3, acc[3][3]);
    }
    __syncthreads();
  }
#pragma unroll
  for (int i = 0; i < 4; ++i) {
    const int m = m0 + (ty << 2) + i;
#pragma unroll
    for (int j = 0; j < 4; ++j) {
      const int n = n0 + (tx << 2) + j;
      double v = acc[i][j];
      if (ADD1) v += (double)a1v[n];
      if (ADD2) v += (double)a2v[n];
      float f = (float)v;
      if (RELU) f = fmaxf(f, 0.0f);
      C[(size_t)m * N + n] = f;
    }
  }
}

// ------------------------------------------------------------------
// Per-row top-64 via 4-pass radix select on monotonic uint keys.
// Tie-break: smallest index first (matches lax.top_k stable ordering).
// ------------------------------------------------------------------
__global__ __launch_bounds__(256) void topk_kernel(const float* __restrict__ buf,
                                                   float* __restrict__ vals,
                                                   int* __restrict__ idxs) {
  __shared__ unsigned m[F_DIM];       // 48 KB
  __shared__ unsigned hist[256];
  __shared__ unsigned eqlist[1024];
  __shared__ int sb, sgt, seq;
  const int tid = threadIdx.x;
  const int t = blockIdx.x;
  const float* row = buf + (size_t)t * F_DIM;
  for (int e = tid; e < F_DIM; e += 256) {
    unsigned u = __float_as_uint(row[e]);
    m[e] = (u & 0x80000000u) ? ~u : (u | 0x80000000u);
  }
  __syncthreads();
  unsigned prefix = 0;
  int need = K_TOP;
  for (int pass = 0; pass < 4; ++pass) {
    hist[tid] = 0;
    __syncthreads();
    const int shb = 24 - 8 * pass;
    for (int e = tid; e < F_DIM; e += 256) {
      unsigned v = m[e];
      unsigned hi = (pass == 0) ? 0u : (v >> ((32 - 8 * pass) & 31));
      unsigned want = (pass == 0) ? 0u : prefix;
      if (hi == want) atomicAdd(&hist[(v >> shb) & 0xFFu], 1u);
    }
    __syncthreads();
    for (int off = 1; off < 256; off <<= 1) {  // inclusive suffix sums
      unsigned v = (tid + off < 256) ? hist[tid + off] : 0u;
      __syncthreads();
      hist[tid] += v;
      __syncthreads();
    }
    unsigned s0 = hist[tid];
    unsigned s1 = (tid < 255) ? hist[tid + 1] : 0u;
    if (s0 >= (unsigned)need && s1 < (unsigned)need) sb = tid;
    __syncthreads();
    const int b = sb;
    const unsigned above = (b < 255) ? hist[b + 1] : 0u;
    __syncthreads();
    need -= (int)above;
    prefix = (prefix << 8) | (unsigned)b;
  }
  const unsigned T = prefix;
  const int rneed = need;  // 1..count_eq
  if (tid == 0) { sgt = 0; seq = 0; }
  __syncthreads();
  for (int e = tid; e < F_DIM; e += 256) {
    unsigned v = m[e];
    if (v > T) {
      int p = atomicAdd(&sgt, 1);
      unsigned u = (v & 0x80000000u) ? (v ^ 0x80000000u) : ~v;
      vals[t * K_TOP + p] = __uint_as_float(u);
      idxs[t * K_TOP + p] = e;
    } else if (v == T) {
      int p = atomicAdd(&seq, 1);
      if (p < 1024) eqlist[p] = (unsigned)e;
    }
  }
  __syncthreads();
  const int gt = sgt;  // == K_TOP - rneed
  const int eqc = seq;
  const float tval = __uint_as_float((T & 0x80000000u) ? (T ^ 0x80000000u) : ~T);
  if (eqc <= 1024) {
    for (int it = 0; it < rneed; ++it) {
      unsigned best = 0xFFFFFFFFu;
      for (int p = tid; p < eqc; p += 256) best = min(best, eqlist[p]);
      hist[tid] = best;
      __syncthreads();
      for (int off = 128; off; off >>= 1) {
        if (tid < off) hist[tid] = min(hist[tid], hist[tid + off]);
        __syncthreads();
      }
      const unsigned sel = hist[0];
      if (tid == 0) {
        vals[t * K_TOP + gt + it] = tval;
        idxs[t * K_TOP + gt + it] = (int)sel;
      }
      for (int p = tid; p < eqc; p += 256)
        if (eqlist[p] == sel) eqlist[p] = 0xFFFFFFFFu;
      __syncthreads();
    }
  } else {  // pathological tie flood: sequential fallback (never in practice)
    if (tid == 0) {
      int taken = 0;
      for (int e = 0; e < F_DIM && taken < rneed; ++e)
        if (m[e] == T) {
          vals[t * K_TOP + gt + taken] = tval;
          idxs[t * K_TOP + gt + taken] = e;
          ++taken;
        }
    }
  }
}

// ------------------------------------------------------------------
// Scatter contribs: one wave per (token, active-slot).
// approx[t, i] += val * V[i, j] over CSR column j.
// ------------------------------------------------------------------
__global__ __launch_bounds__(256) void scatter_kernel(
    const float* __restrict__ up_vals, const int* __restrict__ up_idx,
    const float* __restrict__ csr_vals, const unsigned short* __restrict__ csr_rows,
    const int* __restrict__ col_cnt, float* __restrict__ buf) {
  const int pair = blockIdx.x * 4 + (threadIdx.x >> 6);
  const int lane = threadIdx.x & 63;
  const int t = pair >> 6;
  const int s = pair & 63;
  const float val = up_vals[t * K_TOP + s];
  if (val == 0.0f) return;
  const int j = up_idx[t * K_TOP + s];
  const int cnt = min(col_cnt[j], COL_CAP);
  float* dst = buf + (size_t)t * F_DIM;
  for (int e = lane; e < cnt; e += 64) {
    int i = csr_rows[j * COL_CAP + e];
    atomicAdd(dst + i, val * csr_vals[j * COL_CAP + e]);
  }
}

// ------------------------------------------------------------------
// Transpose W_dec_down [768][12288] -> [12288][768] for coalesced decode.
// ------------------------------------------------------------------
__global__ void transpose_kernel(const float* __restrict__ in,
                                 float* __restrict__ out) {
  __shared__ float tile[32][33];
  const int f0 = blockIdx.x * 32, d0 = blockIdx.y * 32;
  for (int rr = threadIdx.y; rr < 32; rr += 8)
    tile[rr][threadIdx.x] = in[(size_t)(d0 + rr) * F_DIM + f0 + threadIdx.x];
  __syncthreads();
  for (int rr = threadIdx.y; rr < 32; rr += 8)
    out[(size_t)(f0 + rr) * D_DIM + d0 + threadIdx.x] = tile[threadIdx.x][rr];
}

// ------------------------------------------------------------------
// Decode: recon[t,:] = sum_j dval_j * Wt[didx_j,:] + b_dec_down
// ------------------------------------------------------------------
__global__ __launch_bounds__(256) void decode_kernel(
    const float* __restrict__ dvals, const int* __restrict__ didx,
    const float* __restrict__ Wt, const float* __restrict__ bdd,
    float* __restrict__ out) {
  const int t = blockIdx.x;
  const int d = threadIdx.x;
  double a0 = 0.0, a1 = 0.0, a2 = 0.0;
  for (int s = 0; s < K_TOP; ++s) {
    const float v = dvals[t * K_TOP + s];
    const int f = didx[t * K_TOP + s];
    const float* w = Wt + (size_t)f * D_DIM;
    a0 += (double)v * (double)w[d];
    a1 += (double)v * (double)w[d + 256];
    a2 += (double)v * (double)w[d + 512];
  }
  float* o = out + (size_t)t * D_DIM;
  o[d] = (float)(a0 + (double)bdd[d]);
  o[d + 256] = (float)(a1 + (double)bdd[d + 256]);
  o[d + 512] = (float)(a2 + (double)bdd[d + 512]);
}

// ------------------------------------------------------------------
extern "C" void kernel_launch(void* const* d_in, const int* in_sizes, int n_in,
                              void* d_out, int out_size, void* d_ws, size_t ws_size,
                              hipStream_t stream) {
  const float* x_up  = (const float*)d_in[0];
  const float* x_res = (const float*)d_in[1];
  const float* Weu   = (const float*)d_in[2];   // [F][D]
  const float* beu   = (const float*)d_in[3];   // [F]
  const float* bdu   = (const float*)d_in[4];   // [D]
  const float* Wdu   = (const float*)d_in[5];   // [D][F]
  const float* Wed   = (const float*)d_in[6];   // [F][D]
  const float* bed   = (const float*)d_in[7];   // [F]
  const float* bdd   = (const float*)d_in[8];   // [D]
  const float* Wdd   = (const float*)d_in[9];   // [D][F]
  const void*  mask  = d_in[10];                // [F][F] dtype detected on device
  float* out = (float*)d_out;

  char* w = (char*)d_ws;
  float*          buf    = (float*)(w);                            // 201326592 B
  float*          wt     = (float*)(w + 201326592);                //  37748736 B
  float*          csrv   = (float*)(w + 239075328);                //  12582912 B
  unsigned short* csrr   = (unsigned short*)(w + 251658240);       //   6291456 B
  int*            colcnt = (int*)(w + 257949696);                  //     49152 B
  float*          biasc  = (float*)(w + 257998848);                //     49152 B
  float*          upv    = (float*)(w + 258048000);
  int*            upi    = (int*)(w + 259096576);
  float*          dnv    = (float*)(w + 260145152);
  int*            dni    = (int*)(w + 261193728);
  int*            mode   = (int*)(w + 262242304);
  const size_t NEED = 262242560;
  if (ws_size < NEED) return;  // visible failure instead of corruption

  hipMemsetAsync(colcnt, 0, F_DIM * sizeof(int), stream);
  detect_mask_kernel<<<1, 1024, 0, stream>>>(mask, mode);
  count_fill_kernel<<<8192, 256, 0, stream>>>(mask, mode, colcnt, csrr);
  csr_vals_kernel<<<F_DIM / 4, 256, 0, stream>>>(Wdu, Wed, csrr, colcnt, csrv);
  bias_contrib_kernel<<<F_DIM / 4, 256, 0, stream>>>(bdu, Wed, biasc);
  // up_pre = relu((x_up - b_dec_up) @ W_enc_up.T + b_enc_up)
  gemm_f64<1, 1, 1, 0><<<dim3(F_DIM / 64, M_DIM / 64), 256, 0, stream>>>(
      x_up, Weu, buf, bdu, beu, beu, M_DIM, F_DIM, D_DIM);
  topk_kernel<<<M_DIM, 256, 0, stream>>>(buf, upv, upi);
  // approx(base) = x_resid @ W_enc_down.T + bias_contrib + b_enc_down
  gemm_f64<0, 0, 1, 1><<<dim3(F_DIM / 64, M_DIM / 64), 256, 0, stream>>>(
      x_res, Wed, buf, bdu, biasc, bed, M_DIM, F_DIM, D_DIM);
  scatter_kernel<<<M_DIM * K_TOP / 4, 256, 0, stream>>>(upv, upi, csrv, csrr,
                                                        colcnt, buf);
  transpose_kernel<<<dim3(F_DIM / 32, D_DIM / 32), dim3(32, 8), 0, stream>>>(Wdd, wt);
  topk_kernel<<<M_DIM, 256, 0, stream>>>(buf, dnv, dni);
  decode_kernel<<<M_DIM, 256, 0, stream>>>(dnv, dni, wt, bdd, out);
}

// Round 2
// 6461.216 us; speedup vs baseline: 1.2529x; 1.2529x over previous
//
#include <hip/hip_runtime.h>
#include <hip/hip_bf16.h>
#include <stdint.h>

#define F_DIM 12288
#define D_DIM 768
#define M_DIM 4096   // B*S tokens
#define K_TOP 64
#define COL_CAP 256
#define NCAND 96     // fp32 candidates refined in fp64 per row
#define QTOK 1024    // tokens per downstream quarter
#define LP 132       // padded LDS leading dim in GEMM

// ------------------------------------------------------------------
// Mask dtype detection: 0 = int32, 1 = uint8/bool, 2 = float32
// ------------------------------------------------------------------
__global__ void detect_mask_kernel(const void* mask, int* mode) {
  __shared__ int weird, misal;
  if (threadIdx.x == 0) { weird = 0; misal = 0; }
  __syncthreads();
  const unsigned char* p = (const unsigned char*)mask;
  for (int i = threadIdx.x; i < (1 << 20); i += blockDim.x) {
    unsigned char b = p[i];
    if (b != 0) {
      if (b != 1) atomicOr(&weird, 1);
      else if (i & 3) atomicOr(&misal, 1);
    }
  }
  __syncthreads();
  if (threadIdx.x == 0) mode[0] = weird ? 2 : (misal ? 1 : 0);
}

// ------------------------------------------------------------------
// CSR build by column (up-feature). ~123 entries/col, cap 256.
// ------------------------------------------------------------------
__global__ void count_fill_kernel(const void* mask, const int* mode_p,
                                  int* col_cnt, unsigned short* rows) {
  const int mode = *mode_p;
  const int total = F_DIM * F_DIM;
  for (int e = blockIdx.x * blockDim.x + threadIdx.x; e < total;
       e += gridDim.x * blockDim.x) {
    bool set;
    if (mode == 0)      set = ((const int*)mask)[e] != 0;
    else if (mode == 1) set = ((const unsigned char*)mask)[e] != 0;
    else                set = ((const float*)mask)[e] != 0.0f;
    if (set) {
      int j = e % F_DIM;  // up feature (column)
      int i = e / F_DIM;  // down feature (row)
      int pos = atomicAdd(&col_cnt[j], 1);
      if (pos < COL_CAP) rows[j * COL_CAP + pos] = (unsigned short)i;
    }
  }
}

// ------------------------------------------------------------------
// Transpose [768][12288] -> [12288][768] (used for Wdu and Wdd).
// ------------------------------------------------------------------
__global__ void transpose_kernel(const float* __restrict__ in,
                                 float* __restrict__ out) {
  __shared__ float tile[32][33];
  const int f0 = blockIdx.x * 32, d0 = blockIdx.y * 32;
  for (int rr = threadIdx.y; rr < 32; rr += 8)
    tile[rr][threadIdx.x] = in[(size_t)(d0 + rr) * F_DIM + f0 + threadIdx.x];
  __syncthreads();
  for (int rr = threadIdx.y; rr < 32; rr += 8)
    out[(size_t)(f0 + rr) * D_DIM + d0 + threadIdx.x] = tile[threadIdx.x][rr];
}

// ------------------------------------------------------------------
// Masked virtual values, fp64 acc: V[i,j] = dot(Wed[i,:], WduT[j,:]).
// One block per column j; 4 waves split the nonzeros (serial /4).
// ------------------------------------------------------------------
__global__ __launch_bounds__(256) void csr_vals_kernel(
    const float* __restrict__ WduT, const float* __restrict__ Wed,
    const unsigned short* __restrict__ rows, const int* __restrict__ col_cnt,
    float* __restrict__ vals) {
  const int j = blockIdx.x;
  const int wid = threadIdx.x >> 6, lane = threadIdx.x & 63;
  double wu[12];
  const float* wc = WduT + (size_t)j * D_DIM;
#pragma unroll
  for (int c = 0; c < 12; ++c) wu[c] = (double)wc[lane + (c << 6)];
  const int cnt = min(col_cnt[j], COL_CAP);
  for (int n = wid; n < cnt; n += 4) {
    const int i = rows[j * COL_CAP + n];
    const float* wr = Wed + (size_t)i * D_DIM;
    double s = 0.0;
#pragma unroll
    for (int c = 0; c < 12; ++c)
      s = fma(wu[c], (double)wr[lane + (c << 6)], s);
#pragma unroll
    for (int off = 32; off; off >>= 1) s += __shfl_xor(s, off);
    if (lane == 0) vals[j * COL_CAP + n] = (float)s;
  }
}

// ------------------------------------------------------------------
// bias_contrib[f] = dot(b_dec_up, Wed[f,:])  (fp64 acc)
// ------------------------------------------------------------------
__global__ __launch_bounds__(256) void bias_contrib_kernel(
    const float* __restrict__ bdu, const float* __restrict__ Wed,
    float* __restrict__ out) {
  const int f = blockIdx.x * 4 + (threadIdx.x >> 6);
  const int lane = threadIdx.x & 63;
  double s = 0.0;
#pragma unroll
  for (int c = 0; c < 12; ++c) {
    int d = lane + (c << 6);
    s += (double)bdu[d] * (double)Wed[(size_t)f * D_DIM + d];
  }
#pragma unroll
  for (int off = 32; off; off >>= 1) s += __shfl_xor(s, off);
  if (lane == 0) out[f] = (float)s;
}

// ------------------------------------------------------------------
// xsub = x_up - b_dec_up (fp32, the exact values GEMM + refine share)
// ------------------------------------------------------------------
__global__ void xsub_kernel(const float* __restrict__ x,
                            const float* __restrict__ b,
                            float* __restrict__ o) {
  const size_t base = (size_t)blockIdx.x * D_DIM;
  const int d = threadIdx.x;
  o[base + d]       = x[base + d]       - b[d];
  o[base + d + 256] = x[base + d + 256] - b[d + 256];
  o[base + d + 512] = x[base + d + 512] - b[d + 512];
}

// ------------------------------------------------------------------
// fp32 GEMM: C[m,n] = post(sum_k A[m,k]*B[n,k]), 128x128 tile,
// 8x8/thread, K-step 32, reg-prefetch of next tile, LDS [k][m] (LP pad).
// ------------------------------------------------------------------
template <int ADD1, int ADD2, int RELU>
__global__ __launch_bounds__(256) void gemm_f32(
    const float* __restrict__ A, const float* __restrict__ B,
    float* __restrict__ C, const float* __restrict__ v1,
    const float* __restrict__ v2, int M) {
  const int N = F_DIM, K = D_DIM;
  __shared__ float As[32][LP];
  __shared__ float Bs[32][LP];
  const int tid = threadIdx.x;
  const int m0 = blockIdx.y << 7, n0 = blockIdx.x << 7;
  const int tx = tid & 15, ty = tid >> 4;
  const int r0 = tid >> 3, k4 = tid & 7;
  float4 ra[4], rb[4];
  float acc[8][8];
#pragma unroll
  for (int i = 0; i < 8; ++i)
#pragma unroll
    for (int j = 0; j < 8; ++j) acc[i][j] = 0.f;
  const float* Ab = A + (size_t)(m0 + r0) * K + (k4 << 2);
  const float* Bb = B + (size_t)(n0 + r0) * K + (k4 << 2);
#pragma unroll
  for (int q = 0; q < 4; ++q) {
    ra[q] = *(const float4*)(Ab + (size_t)(q << 5) * K);
    rb[q] = *(const float4*)(Bb + (size_t)(q << 5) * K);
  }
  for (int t = 0; t < K / 32; ++t) {
    __syncthreads();
#pragma unroll
    for (int q = 0; q < 4; ++q) {
      const int row = r0 + (q << 5);
      As[(k4 << 2) + 0][row] = ra[q].x; As[(k4 << 2) + 1][row] = ra[q].y;
      As[(k4 << 2) + 2][row] = ra[q].z; As[(k4 << 2) + 3][row] = ra[q].w;
      Bs[(k4 << 2) + 0][row] = rb[q].x; Bs[(k4 << 2) + 1][row] = rb[q].y;
      Bs[(k4 << 2) + 2][row] = rb[q].z; Bs[(k4 << 2) + 3][row] = rb[q].w;
    }
    __syncthreads();
    if (t + 1 < K / 32) {
      const int k0 = (t + 1) << 5;
#pragma unroll
      for (int q = 0; q < 4; ++q) {
        ra[q] = *(const float4*)(Ab + (size_t)(q << 5) * K + k0);
        rb[q] = *(const float4*)(Bb + (size_t)(q << 5) * K + k0);
      }
    }
#pragma unroll 8
    for (int k = 0; k < 32; ++k) {
      const float4 a0 = *(const float4*)(&As[k][ty << 3]);
      const float4 a1 = *(const float4*)(&As[k][(ty << 3) + 4]);
      const float4 b0 = *(const float4*)(&Bs[k][tx << 3]);
      const float4 b1 = *(const float4*)(&Bs[k][(tx << 3) + 4]);
      const float a[8] = {a0.x, a0.y, a0.z, a0.w, a1.x, a1.y, a1.z, a1.w};
      const float b[8] = {b0.x, b0.y, b0.z, b0.w, b1.x, b1.y, b1.z, b1.w};
#pragma unroll
      for (int i = 0; i < 8; ++i)
#pragma unroll
        for (int j = 0; j < 8; ++j) acc[i][j] = fmaf(a[i], b[j], acc[i][j]);
    }
  }
#pragma unroll
  for (int i = 0; i < 8; ++i) {
    const size_t m = m0 + (ty << 3) + i;
#pragma unroll
    for (int jb = 0; jb < 2; ++jb) {
      const int n = n0 + (tx << 3) + (jb << 2);
      float4 o;
      float* po = &o.x;
#pragma unroll
      for (int j = 0; j < 4; ++j) {
        float v = acc[i][(jb << 2) + j];
        if (ADD1) v += v1[n + j];
        if (ADD2) v += v2[n + j];
        if (RELU) v = fmaxf(v, 0.f);
        po[j] = v;
      }
      *(float4*)(C + m * N + n) = o;
    }
  }
}

// ------------------------------------------------------------------
// Fused top-k: fp32 radix-select top-96 candidates, refine each in
// fp64 (recompute the 768-dot), rank-select exact top-64 with
// lax.top_k tie-break (value desc, index asc).
// DOWN adds fp64 contribs + biases; UP applies relu.
// ------------------------------------------------------------------
template <int DOWN>
__global__ __launch_bounds__(256) void topk_refine_kernel(
    const float* __restrict__ fastv, const double* __restrict__ contribs,
    const float* __restrict__ X, const float* __restrict__ W,
    const float* __restrict__ add1, const float* __restrict__ add2,
    float* __restrict__ outv, int* __restrict__ outi, int t0) {
  __shared__ unsigned keys[F_DIM];   // 48 KB
  __shared__ float xs[D_DIM];
  __shared__ unsigned hist[256];
  __shared__ int cidx[128];
  __shared__ double cval[128];
  __shared__ int sb, snc;
  const int tid = threadIdx.x;
  const int t = blockIdx.x;
  const float* frow = fastv + (size_t)t * F_DIM;
  const double* crow = contribs + (size_t)t * F_DIM;
  for (int e = tid; e < F_DIM; e += 256) {
    float v = frow[e];
    if (DOWN) v = (float)((double)v + crow[e]);
    unsigned u = __float_as_uint(v);
    keys[e] = (u & 0x80000000u) ? ~u : (u | 0x80000000u);
  }
  for (int d = tid; d < D_DIM; d += 256) xs[d] = X[(size_t)t * D_DIM + d];
  __syncthreads();
  // 4-pass radix: threshold T with count(key > T) < NCAND <= count(key >= T)
  unsigned prefix = 0;
  int need = NCAND;
  for (int pass = 0; pass < 4; ++pass) {
    hist[tid] = 0;
    __syncthreads();
    const int shb = 24 - 8 * pass;
    for (int e = tid; e < F_DIM; e += 256) {
      unsigned v = keys[e];
      unsigned hi = (pass == 0) ? 0u : (v >> ((32 - 8 * pass) & 31));
      unsigned want = (pass == 0) ? 0u : prefix;
      if (hi == want) atomicAdd(&hist[(v >> shb) & 0xFFu], 1u);
    }
    __syncthreads();
    for (int off = 1; off < 256; off <<= 1) {  // inclusive suffix sums
      unsigned v = (tid + off < 256) ? hist[tid + off] : 0u;
      __syncthreads();
      hist[tid] += v;
      __syncthreads();
    }
    unsigned s0 = hist[tid];
    unsigned s1 = (tid < 255) ? hist[tid + 1] : 0u;
    if (s0 >= (unsigned)need && s1 < (unsigned)need) sb = tid;
    __syncthreads();
    const int b = sb;
    const unsigned above = (b < 255) ? hist[b + 1] : 0u;
    __syncthreads();
    need -= (int)above;
    prefix = (prefix << 8) | (unsigned)b;
  }
  const unsigned T = prefix;
  // collect candidates: all key>T, then fill from key==T up to NCAND
  if (tid == 0) snc = 0;
  __syncthreads();
  for (int e = tid; e < F_DIM; e += 256)
    if (keys[e] > T) { int p = atomicAdd(&snc, 1); if (p < 128) cidx[p] = e; }
  __syncthreads();
  for (int e = tid; e < F_DIM; e += 256)
    if (keys[e] == T) { int p = atomicAdd(&snc, 1); if (p < NCAND) cidx[p] = e; }
  __syncthreads();
  const int ncand = min(snc, NCAND);
  // fp64 refinement: wave-per-candidate round robin
  const int wid = tid >> 6, lane = tid & 63;
  for (int c = wid; c < ncand; c += 4) {
    const int e = cidx[c];
    const float* wr = W + (size_t)e * D_DIM;
    double s = 0.0;
#pragma unroll
    for (int q = 0; q < 12; ++q)
      s = fma((double)xs[lane + (q << 6)], (double)wr[lane + (q << 6)], s);
#pragma unroll
    for (int off = 32; off; off >>= 1) s += __shfl_xor(s, off);
    if (lane == 0) {
      double v = s + (double)add1[e];
      if (DOWN) v += (double)add2[e] + crow[e];
      else v = v > 0.0 ? v : 0.0;
      cval[c] = v;
    }
  }
  __syncthreads();
  // exact rank select (96^2 pairwise, tie-break by smaller index)
  for (int c = tid; c < ncand; c += 256) {
    const double v = cval[c];
    const int e = cidx[c];
    int r = 0;
    for (int p = 0; p < ncand; ++p) {
      const double vp = cval[p];
      if (vp > v || (vp == v && cidx[p] < e)) ++r;
    }
    if (r < K_TOP) {
      outv[(size_t)(t0 + t) * K_TOP + r] = (float)v;
      outi[(size_t)(t0 + t) * K_TOP + r] = e;
    }
  }
}

// ------------------------------------------------------------------
// Scatter contribs into fp64 accumulator (native f64 atomics).
// One wave per (token, active-slot).
// ------------------------------------------------------------------
__global__ __launch_bounds__(256) void scatter_kernel(
    const float* __restrict__ up_vals, const int* __restrict__ up_idx,
    const float* __restrict__ csr_vals, const unsigned short* __restrict__ csr_rows,
    const int* __restrict__ col_cnt, double* __restrict__ contribs, int t0) {
  const int pair = blockIdx.x * 4 + (threadIdx.x >> 6);
  const int lane = threadIdx.x & 63;
  const int tl = pair >> 6;
  const int s = pair & 63;
  const float val = up_vals[(size_t)(t0 + tl) * K_TOP + s];
  if (val == 0.0f) return;
  const int j = up_idx[(size_t)(t0 + tl) * K_TOP + s];
  const int cnt = min(col_cnt[j], COL_CAP);
  double* dst = contribs + (size_t)tl * F_DIM;
  for (int e = lane; e < cnt; e += 64) {
    int i = csr_rows[j * COL_CAP + e];
    unsafeAtomicAdd(dst + i, (double)val * (double)csr_vals[j * COL_CAP + e]);
  }
}

// ------------------------------------------------------------------
// Decode: recon[t,:] = sum_s v_s * WddT[f_s,:] + b_dec_down  (fp32)
// ------------------------------------------------------------------
__global__ __launch_bounds__(256) void decode_kernel(
    const float* __restrict__ dvals, const int* __restrict__ didx,
    const float* __restrict__ Wt, const float* __restrict__ bdd,
    float* __restrict__ out) {
  const int t = blockIdx.x, d = threadIdx.x;
  float a0 = bdd[d], a1 = bdd[d + 256], a2 = bdd[d + 512];
  for (int s = 0; s < K_TOP; ++s) {
    const float v = dvals[(size_t)t * K_TOP + s];
    const float* wr = Wt + (size_t)didx[(size_t)t * K_TOP + s] * D_DIM;
    a0 = fmaf(v, wr[d], a0);
    a1 = fmaf(v, wr[d + 256], a1);
    a2 = fmaf(v, wr[d + 512], a2);
  }
  float* o = out + (size_t)t * D_DIM;
  o[d] = a0; o[d + 256] = a1; o[d + 512] = a2;
}

// ------------------------------------------------------------------
extern "C" void kernel_launch(void* const* d_in, const int* in_sizes, int n_in,
                              void* d_out, int out_size, void* d_ws, size_t ws_size,
                              hipStream_t stream) {
  const float* x_up  = (const float*)d_in[0];
  const float* x_res = (const float*)d_in[1];
  const float* Weu   = (const float*)d_in[2];   // [F][D]
  const float* beu   = (const float*)d_in[3];   // [F]
  const float* bdu   = (const float*)d_in[4];   // [D]
  const float* Wdu   = (const float*)d_in[5];   // [D][F]
  const float* Wed   = (const float*)d_in[6];   // [F][D]
  const float* bed   = (const float*)d_in[7];   // [F]
  const float* bdd   = (const float*)d_in[8];   // [D]
  const float* Wdd   = (const float*)d_in[9];   // [D][F]
  const void*  mask  = d_in[10];
  float* out = (float*)d_out;

  char* w = (char*)d_ws;
  float*          buf    = (float*)(w);                      // 201326592 B
  float*          csrv   = (float*)(w + 201326592);          //  12582912
  unsigned short* csrr   = (unsigned short*)(w + 213909504); //   6291456
  int*            colcnt = (int*)(w + 220200960);            //     49152
  float*          biasc  = (float*)(w + 220250112);          //     49152
  float*          xsub   = (float*)(w + 220299264);          //  12582912
  float*          upv    = (float*)(w + 232882176);
  int*            upi    = (int*)(w + 233930752);
  float*          dnv    = (float*)(w + 234979328);
  int*            dni    = (int*)(w + 236027904);
  int*            mode   = (int*)(w + 237076480);
  if (ws_size < 237076736) return;
  // downstream per-quarter: base fp32 [QTOK][F] in buf[0:50.3MB],
  // contribs fp64 [QTOK][F] right after (inside buf's 201 MB).
  double* contribs = (double*)(w + 50331648);

  hipMemsetAsync(colcnt, 0, F_DIM * sizeof(int), stream);
  detect_mask_kernel<<<1, 1024, 0, stream>>>(mask, mode);
  count_fill_kernel<<<8192, 256, 0, stream>>>(mask, mode, colcnt, csrr);
  // WduT staged in buf (dead until GEMM1), then consumed by csr_vals.
  transpose_kernel<<<dim3(F_DIM / 32, D_DIM / 32), dim3(32, 8), 0, stream>>>(Wdu, buf);
  csr_vals_kernel<<<F_DIM, 256, 0, stream>>>(buf, Wed, csrr, colcnt, csrv);
  bias_contrib_kernel<<<F_DIM / 4, 256, 0, stream>>>(bdu, Wed, biasc);
  xsub_kernel<<<M_DIM, 256, 0, stream>>>(x_up, bdu, xsub);
  // upstream: fp32 pre-acts -> fused topk + fp64 refine
  gemm_f32<1, 0, 1><<<dim3(96, 32), 256, 0, stream>>>(xsub, Weu, buf, beu, beu, M_DIM);
  topk_refine_kernel<0><<<M_DIM, 256, 0, stream>>>(buf, contribs, xsub, Weu,
                                                   beu, beu, upv, upi, 0);
  // downstream in 4 token-quarters: base fp32 + contribs fp64
  for (int qq = 0; qq < 4; ++qq) {
    const int t0 = qq * QTOK;
    gemm_f32<1, 1, 0><<<dim3(96, QTOK / 128), 256, 0, stream>>>(
        x_res + (size_t)t0 * D_DIM, Wed, buf, biasc, bed, QTOK);
    hipMemsetAsync(contribs, 0, (size_t)QTOK * F_DIM * sizeof(double), stream);
    scatter_kernel<<<QTOK * K_TOP / 4, 256, 0, stream>>>(upv, upi, csrv, csrr,
                                                         colcnt, contribs, t0);
    topk_refine_kernel<1><<<QTOK, 256, 0, stream>>>(
        buf, contribs, x_res + (size_t)t0 * D_DIM, Wed, biasc, bed, dnv, dni, t0);
  }
  // WddT into buf (now dead), then decode
  transpose_kernel<<<dim3(F_DIM / 32, D_DIM / 32), dim3(32, 8), 0, stream>>>(Wdd, buf);
  decode_kernel<<<M_DIM, 256, 0, stream>>>(dnv, dni, buf, bdd, out);
}

// Round 3
// 4293.510 us; speedup vs baseline: 1.8855x; 1.5049x over previous
//
#include <hip/hip_runtime.h>
#include <hip/hip_bf16.h>
#include <stdint.h>

#define F_DIM 12288
#define D_DIM 768
#define M_DIM 4096   // B*S tokens
#define K_TOP 64
#define CAP   256    // CSR capacity per row/col (mean ~123, sd ~11)
#define NC    128    // candidates refined in fp64 per token
#define LDAP  40     // LDS tile row stride in bf16 elems (32 data + 8 pad = 80 B)

typedef __attribute__((ext_vector_type(8))) short short8;
typedef __attribute__((ext_vector_type(4))) float f32x4;
typedef __attribute__((ext_vector_type(8))) unsigned short ushort8v;
typedef __attribute__((ext_vector_type(4))) unsigned short ushort4v;

__device__ __forceinline__ unsigned short f2bf_rne(float f) {
  unsigned u = __float_as_uint(f);
  return (unsigned short)((u + 0x7FFFu + ((u >> 16) & 1u)) >> 16);
}
__device__ __forceinline__ float bf2f(unsigned short h) {
  return __uint_as_float((unsigned)h << 16);
}
__device__ __forceinline__ unsigned key16u(unsigned u16) {  // monotone map of bf16 bits
  return (u16 & 0x8000u) ? (~u16 & 0xFFFFu) : (u16 | 0x8000u);
}
__device__ __forceinline__ unsigned key16f(float v) {  // monotone (non-strict) 16-bit key
  unsigned u = __float_as_uint(v);
  unsigned k = (u & 0x80000000u) ? ~u : (u | 0x80000000u);
  return k >> 16;
}

// ------------------------------------------------------------------
// Mask dtype detection: 0 = int32, 1 = uint8/bool, 2 = float32
// ------------------------------------------------------------------
__global__ void detect_mask_kernel(const void* mask, int* mode) {
  __shared__ int weird, misal;
  if (threadIdx.x == 0) { weird = 0; misal = 0; }
  __syncthreads();
  const unsigned char* p = (const unsigned char*)mask;
  for (int i = threadIdx.x; i < (1 << 20); i += blockDim.x) {
    unsigned char b = p[i];
    if (b != 0) {
      if (b != 1) atomicOr(&weird, 1);
      else if (i & 3) atomicOr(&misal, 1);
    }
  }
  __syncthreads();
  if (threadIdx.x == 0) mode[0] = weird ? 2 : (misal ? 1 : 0);
}

// ------------------------------------------------------------------
// Build BOTH col-CSR (scatter) and row-CSR (refine) in one pass.
// ------------------------------------------------------------------
__global__ void count_fill_kernel(const void* mask, const int* mode_p,
                                  int* col_cnt, int* row_cnt,
                                  unsigned short* colrows, unsigned char* colrpos,
                                  unsigned short* rowcols) {
  const int mode = *mode_p;
  const int total = F_DIM * F_DIM;
  for (int e = blockIdx.x * blockDim.x + threadIdx.x; e < total;
       e += gridDim.x * blockDim.x) {
    bool set;
    if (mode == 0)      set = ((const int*)mask)[e] != 0;
    else if (mode == 1) set = ((const unsigned char*)mask)[e] != 0;
    else                set = ((const float*)mask)[e] != 0.0f;
    if (set) {
      int j = e % F_DIM;  // up feature (column)
      int i = e / F_DIM;  // down feature (row)
      int pc = atomicAdd(&col_cnt[j], 1);
      int pr = atomicAdd(&row_cnt[i], 1);
      if (pc < CAP && pr < CAP) {
        colrows[j * CAP + pc] = (unsigned short)i;
        colrpos[j * CAP + pc] = (unsigned char)pr;
        rowcols[i * CAP + pr] = (unsigned short)j;
      }
    }
  }
}

// ------------------------------------------------------------------
// Transpose [768][12288] -> [12288][768] fp32 (Wdu and Wdd).
// ------------------------------------------------------------------
__global__ void transpose_kernel(const float* __restrict__ in,
                                 float* __restrict__ out) {
  __shared__ float tile[32][33];
  const int f0 = blockIdx.x * 32, d0 = blockIdx.y * 32;
  for (int rr = threadIdx.y; rr < 32; rr += 8)
    tile[rr][threadIdx.x] = in[(size_t)(d0 + rr) * F_DIM + f0 + threadIdx.x];
  __syncthreads();
  for (int rr = threadIdx.y; rr < 32; rr += 8)
    out[(size_t)(f0 + rr) * D_DIM + d0 + threadIdx.x] = tile[threadIdx.x][rr];
}

// ------------------------------------------------------------------
// Masked virtual values fp32: V[i,j] = dot(Wed[i,:], WduT[j,:]).
// Writes both col-layout and row-layout values.
// ------------------------------------------------------------------
__global__ __launch_bounds__(256) void csr_vals_kernel(
    const float* __restrict__ WduT, const float* __restrict__ Wed,
    const unsigned short* __restrict__ colrows,
    const unsigned char* __restrict__ colrpos, const int* __restrict__ col_cnt,
    float* __restrict__ colval, float* __restrict__ rowval) {
  const int j = blockIdx.x;
  const int wid = threadIdx.x >> 6, lane = threadIdx.x & 63;
  float wu[12];
  const float* wc = WduT + (size_t)j * D_DIM;
#pragma unroll
  for (int c = 0; c < 12; ++c) wu[c] = wc[lane + (c << 6)];
  const int cnt = min(col_cnt[j], CAP);
  for (int n = wid; n < cnt; n += 4) {
    const int i = colrows[j * CAP + n];
    const float* wr = Wed + (size_t)i * D_DIM;
    float s = 0.0f;
#pragma unroll
    for (int c = 0; c < 12; ++c) s = fmaf(wu[c], wr[lane + (c << 6)], s);
#pragma unroll
    for (int off = 32; off; off >>= 1) s += __shfl_xor(s, off);
    if (lane == 0) {
      colval[j * CAP + n] = s;
      rowval[(size_t)i * CAP + colrpos[j * CAP + n]] = s;
    }
  }
}

// ------------------------------------------------------------------
// bias_contrib[f] = dot(b_dec_up, Wed[f,:])  (fp64 acc)
// ------------------------------------------------------------------
__global__ __launch_bounds__(256) void bias_contrib_kernel(
    const float* __restrict__ bdu, const float* __restrict__ Wed,
    float* __restrict__ out) {
  const int f = blockIdx.x * 4 + (threadIdx.x >> 6);
  const int lane = threadIdx.x & 63;
  double s = 0.0;
#pragma unroll
  for (int c = 0; c < 12; ++c) {
    int d = lane + (c << 6);
    s += (double)bdu[d] * (double)Wed[(size_t)f * D_DIM + d];
  }
#pragma unroll
  for (int off = 32; off; off >>= 1) s += __shfl_xor(s, off);
  if (lane == 0) out[f] = (float)s;
}

// ------------------------------------------------------------------
// fp32 -> bf16 conversion (optionally subtracting a [768] vector).
// ------------------------------------------------------------------
__global__ void conv_bf16_kernel(const float* __restrict__ src,
                                 const float* __restrict__ sub,
                                 unsigned short* __restrict__ dst, size_t total) {
  size_t i = ((size_t)blockIdx.x * 256 + threadIdx.x) * 4;
  if (i >= total) return;
  float4 v = *(const float4*)(src + i);
  if (sub) {
    int d = (int)(i % D_DIM);
    v.x -= sub[d]; v.y -= sub[d + 1]; v.z -= sub[d + 2]; v.w -= sub[d + 3];
  }
  ushort4v o;
  o[0] = f2bf_rne(v.x); o[1] = f2bf_rne(v.y);
  o[2] = f2bf_rne(v.z); o[3] = f2bf_rne(v.w);
  *(ushort4v*)(dst + i) = o;
}

// ------------------------------------------------------------------
// bf16 MFMA GEMM (BT form): C[m,n] = post(sum_k A[m,k]*B[n,k]) as bf16.
// 128x128 tile, 4 waves (2x2 of 64x64), 16x16x32 MFMA, BK=32,
// double-buffered LDS (pad-40 rows: conflict-free b128 frag reads),
// reg-staged global loads issued before MFMA, XCD-swizzled blockIdx.
// ------------------------------------------------------------------
template <int ADDB2, int RELU>
__global__ __launch_bounds__(256) void gemm_bf16(
    const unsigned short* __restrict__ A,  // [M][768] bf16
    const unsigned short* __restrict__ B,  // [12288][768] bf16
    unsigned short* __restrict__ C,        // [M][12288] bf16
    const float* __restrict__ b1, const float* __restrict__ b2) {
  __shared__ unsigned short Asl[2][128 * LDAP];
  __shared__ unsigned short Bsl[2][128 * LDAP];
  const int nwg = gridDim.x;              // 3072 (divisible by 8)
  const int cpx = nwg >> 3;
  const int swz = (blockIdx.x & 7) * cpx + (blockIdx.x >> 3);
  const int bx = swz % (F_DIM / 128), by = swz / (F_DIM / 128);
  const int m0 = by << 7, n0 = bx << 7;
  const int t = threadIdx.x;
  const int wid = t >> 6, lane = t & 63;
  const int wr = wid >> 1, wc = wid & 1;
  const int ks = lane >> 4, rl = lane & 15;
  const int sr = t >> 1, sh = (t & 1) << 4;  // staging: row, k-half
  const unsigned short* Ag = A + (size_t)(m0 + sr) * D_DIM + sh;
  const unsigned short* Bg = B + (size_t)(n0 + sr) * D_DIM + sh;
  f32x4 acc[4][4];
#pragma unroll
  for (int mi = 0; mi < 4; ++mi)
#pragma unroll
    for (int ni = 0; ni < 4; ++ni)
#pragma unroll
      for (int r = 0; r < 4; ++r) acc[mi][ni][r] = 0.0f;
  uint4 pa0, pa1, pb0, pb1;
#define GLOAD(kk)                                    \
  {                                                  \
    pa0 = *(const uint4*)(Ag + (kk));                \
    pa1 = *(const uint4*)(Ag + (kk) + 8);            \
    pb0 = *(const uint4*)(Bg + (kk));                \
    pb1 = *(const uint4*)(Bg + (kk) + 8);            \
  }
#define LWRITE(bufi)                                              \
  {                                                               \
    unsigned short* da = &Asl[bufi][sr * LDAP + sh];              \
    *(uint4*)da = pa0; *(uint4*)(da + 8) = pa1;                   \
    unsigned short* db = &Bsl[bufi][sr * LDAP + sh];              \
    *(uint4*)db = pb0; *(uint4*)(db + 8) = pb1;                   \
  }
  GLOAD(0)
  LWRITE(0)
  __syncthreads();
  const int NSTEP = D_DIM / 32;  // 24
  for (int step = 0; step < NSTEP; ++step) {
    const int cur = step & 1;
    if (step + 1 < NSTEP) GLOAD((step + 1) << 5)
    short8 af[4], bfr[4];
#pragma unroll
    for (int mi = 0; mi < 4; ++mi) {
      int row = (wr << 6) + (mi << 4) + rl;
      af[mi] = *(const short8*)&Asl[cur][row * LDAP + (ks << 3)];
    }
#pragma unroll
    for (int ni = 0; ni < 4; ++ni) {
      int row = (wc << 6) + (ni << 4) + rl;
      bfr[ni] = *(const short8*)&Bsl[cur][row * LDAP + (ks << 3)];
    }
#pragma unroll
    for (int mi = 0; mi < 4; ++mi)
#pragma unroll
      for (int ni = 0; ni < 4; ++ni)
        acc[mi][ni] = __builtin_amdgcn_mfma_f32_16x16x32_bf16(
            af[mi], bfr[ni], acc[mi][ni], 0, 0, 0);
    if (step + 1 < NSTEP) {
      __syncthreads();
      LWRITE(cur ^ 1)
      __syncthreads();
    }
  }
#undef GLOAD
#undef LWRITE
  const int r4 = lane >> 4;
#pragma unroll
  for (int mi = 0; mi < 4; ++mi)
#pragma unroll
    for (int ni = 0; ni < 4; ++ni) {
      const int nn = n0 + (wc << 6) + (ni << 4) + rl;
      float bias = b1[nn];
      if (ADDB2) bias += b2[nn];
#pragma unroll
      for (int r = 0; r < 4; ++r) {
        const int mm = m0 + (wr << 6) + (mi << 4) + (r4 << 2) + r;
        float v = acc[mi][ni][r] + bias;
        if (RELU) v = fmaxf(v, 0.0f);
        C[(size_t)mm * F_DIM + nn] = f2bf_rne(v);
      }
    }
}

// ------------------------------------------------------------------
// UP fused top-k: bf16 row in regs -> 2-pass 16-bit radix top-128
// candidates -> fp64 refine (recompute 768-dot) -> exact rank-64
// (value desc, index asc) -> output (j,val) sorted by index.
// ------------------------------------------------------------------
__global__ __launch_bounds__(256) void topk_up_kernel(
    const unsigned short* __restrict__ Cb, const float* __restrict__ x_up,
    const float* __restrict__ bdu, const float* __restrict__ Weu,
    const float* __restrict__ beu, int* __restrict__ upj,
    float* __restrict__ upval) {
  __shared__ float xs[D_DIM];
  __shared__ unsigned hist[256];
  __shared__ int cidx[NC];
  __shared__ double cval[NC];
  __shared__ int selidx[K_TOP];
  __shared__ double selvd[K_TOP];
  __shared__ int sb, snc;
  const int tid = threadIdx.x, tok = blockIdx.x;
  const unsigned short* row = Cb + (size_t)tok * F_DIM;
  ushort8v ch[6];
#pragma unroll
  for (int c = 0; c < 6; ++c)
    ch[c] = *(const ushort8v*)(row + (c << 11) + (tid << 3));
  for (int d = tid; d < D_DIM; d += 256)
    xs[d] = x_up[(size_t)tok * D_DIM + d] - bdu[d];
  // pass 0 (high byte)
  hist[tid] = 0;
  __syncthreads();
#pragma unroll
  for (int c = 0; c < 6; ++c)
#pragma unroll
    for (int j = 0; j < 8; ++j)
      atomicAdd(&hist[key16u(ch[c][j]) >> 8], 1u);
  __syncthreads();
  for (int off = 1; off < 256; off <<= 1) {
    unsigned v = (tid + off < 256) ? hist[tid + off] : 0u;
    __syncthreads();
    hist[tid] += v;
    __syncthreads();
  }
  {
    unsigned s0 = hist[tid], s1 = (tid < 255) ? hist[tid + 1] : 0u;
    if (s0 >= NC && s1 < NC) sb = tid;
  }
  __syncthreads();
  const unsigned b0 = (unsigned)sb;
  const unsigned above0 = (b0 < 255) ? hist[b0 + 1] : 0u;
  __syncthreads();
  const int need1 = NC - (int)above0;
  // pass 1 (low byte among hi==b0)
  hist[tid] = 0;
  __syncthreads();
#pragma unroll
  for (int c = 0; c < 6; ++c)
#pragma unroll
    for (int j = 0; j < 8; ++j) {
      unsigned k = key16u(ch[c][j]);
      if ((k >> 8) == b0) atomicAdd(&hist[k & 0xFF], 1u);
    }
  __syncthreads();
  for (int off = 1; off < 256; off <<= 1) {
    unsigned v = (tid + off < 256) ? hist[tid + off] : 0u;
    __syncthreads();
    hist[tid] += v;
    __syncthreads();
  }
  {
    unsigned s0 = hist[tid], s1 = (tid < 255) ? hist[tid + 1] : 0u;
    if (s0 >= (unsigned)need1 && s1 < (unsigned)need1) sb = tid;
  }
  __syncthreads();
  const unsigned T = (b0 << 8) | (unsigned)sb;
  if (tid == 0) snc = 0;
  __syncthreads();
#pragma unroll
  for (int c = 0; c < 6; ++c)
#pragma unroll
    for (int j = 0; j < 8; ++j)
      if (key16u(ch[c][j]) > T) {
        int p = atomicAdd(&snc, 1);
        if (p < NC) cidx[p] = (c << 11) + (tid << 3) + j;
      }
  __syncthreads();
#pragma unroll
  for (int c = 0; c < 6; ++c)
#pragma unroll
    for (int j = 0; j < 8; ++j)
      if (key16u(ch[c][j]) == T) {
        int p = atomicAdd(&snc, 1);
        if (p < NC) cidx[p] = (c << 11) + (tid << 3) + j;
      }
  __syncthreads();
  const int ncand = min(snc, NC);
  // fp64 refine, wave per candidate
  const int wid = tid >> 6, lane = tid & 63;
  for (int c = wid; c < ncand; c += 4) {
    const int e = cidx[c];
    const float* wrp = Weu + (size_t)e * D_DIM;
    double s = 0.0;
#pragma unroll
    for (int q = 0; q < 12; ++q)
      s = fma((double)xs[lane + (q << 6)], (double)wrp[lane + (q << 6)], s);
#pragma unroll
    for (int off = 32; off; off >>= 1) s += __shfl_xor(s, off);
    if (lane == 0) {
      double v = s + (double)beu[e];
      cval[c] = v > 0.0 ? v : 0.0;
    }
  }
  __syncthreads();
  for (int c = tid; c < ncand; c += 256) {
    const double v = cval[c];
    const int e = cidx[c];
    int r = 0;
    for (int p = 0; p < ncand; ++p) {
      double vp = cval[p];
      if (vp > v || (vp == v && cidx[p] < e)) ++r;
    }
    if (r < K_TOP) { selidx[r] = e; selvd[r] = v; }
  }
  __syncthreads();
  if (tid < K_TOP) {
    const int e = selidx[tid];
    int pos = 0;
    for (int p = 0; p < K_TOP; ++p) pos += (selidx[p] < e);
    upj[(size_t)tok * K_TOP + pos] = e;
    upval[(size_t)tok * K_TOP + pos] = (float)selvd[tid];
  }
}

// ------------------------------------------------------------------
// DOWN fused top-k: bf16 base row -> LDS fp32, scatter contribs via
// col-CSR (LDS float atomics), radix top-128, fp64 refine with exact
// contrib via row-CSR + binary search over sorted active-64.
// ------------------------------------------------------------------
__global__ __launch_bounds__(256) void topk_dn_kernel(
    const unsigned short* __restrict__ Cb, const float* __restrict__ x_res,
    const float* __restrict__ Wed, const float* __restrict__ biasc,
    const float* __restrict__ bed, const int* __restrict__ upj,
    const float* __restrict__ upval, const int* __restrict__ col_cnt,
    const unsigned short* __restrict__ colrows, const float* __restrict__ colval,
    const int* __restrict__ row_cnt, const unsigned short* __restrict__ rowcols,
    const float* __restrict__ rowval, float* __restrict__ dnv,
    int* __restrict__ dni) {
  __shared__ float vals[F_DIM];  // 48 KB
  __shared__ float xs[D_DIM];
  __shared__ unsigned hist[256];
  __shared__ int aj[K_TOP];
  __shared__ float av[K_TOP];
  __shared__ int cidx[NC];
  __shared__ double cval[NC];
  __shared__ int sb, snc;
  const int tid = threadIdx.x, tok = blockIdx.x;
  const unsigned short* rowp = Cb + (size_t)tok * F_DIM;
#pragma unroll
  for (int c = 0; c < 6; ++c) {
    ushort8v u = *(const ushort8v*)(rowp + (c << 11) + (tid << 3));
#pragma unroll
    for (int j = 0; j < 8; ++j) vals[(c << 11) + (tid << 3) + j] = bf2f(u[j]);
  }
  if (tid < K_TOP) {
    aj[tid] = upj[(size_t)tok * K_TOP + tid];
    av[tid] = upval[(size_t)tok * K_TOP + tid];
  }
  for (int d = tid; d < D_DIM; d += 256) xs[d] = x_res[(size_t)tok * D_DIM + d];
  __syncthreads();
  const int wid = tid >> 6, lane = tid & 63;
  for (int s = wid; s < K_TOP; s += 4) {
    const int j = aj[s];
    const float v = av[s];
    const int cnt = min(col_cnt[j], CAP);
    for (int n = lane; n < cnt; n += 64)
      atomicAdd(&vals[colrows[j * CAP + n]], v * colval[j * CAP + n]);
  }
  __syncthreads();
  // pass 0
  hist[tid] = 0;
  __syncthreads();
  for (int e = tid; e < F_DIM; e += 256)
    atomicAdd(&hist[key16f(vals[e]) >> 8], 1u);
  __syncthreads();
  for (int off = 1; off < 256; off <<= 1) {
    unsigned v = (tid + off < 256) ? hist[tid + off] : 0u;
    __syncthreads();
    hist[tid] += v;
    __syncthreads();
  }
  {
    unsigned s0 = hist[tid], s1 = (tid < 255) ? hist[tid + 1] : 0u;
    if (s0 >= NC && s1 < NC) sb = tid;
  }
  __syncthreads();
  const unsigned b0 = (unsigned)sb;
  const unsigned above0 = (b0 < 255) ? hist[b0 + 1] : 0u;
  __syncthreads();
  const int need1 = NC - (int)above0;
  // pass 1
  hist[tid] = 0;
  __syncthreads();
  for (int e = tid; e < F_DIM; e += 256) {
    unsigned k = key16f(vals[e]);
    if ((k >> 8) == b0) atomicAdd(&hist[k & 0xFF], 1u);
  }
  __syncthreads();
  for (int off = 1; off < 256; off <<= 1) {
    unsigned v = (tid + off < 256) ? hist[tid + off] : 0u;
    __syncthreads();
    hist[tid] += v;
    __syncthreads();
  }
  {
    unsigned s0 = hist[tid], s1 = (tid < 255) ? hist[tid + 1] : 0u;
    if (s0 >= (unsigned)need1 && s1 < (unsigned)need1) sb = tid;
  }
  __syncthreads();
  const unsigned T = (b0 << 8) | (unsigned)sb;
  if (tid == 0) snc = 0;
  __syncthreads();
  for (int e = tid; e < F_DIM; e += 256)
    if (key16f(vals[e]) > T) {
      int p = atomicAdd(&snc, 1);
      if (p < NC) cidx[p] = e;
    }
  __syncthreads();
  for (int e = tid; e < F_DIM; e += 256)
    if (key16f(vals[e]) == T) {
      int p = atomicAdd(&snc, 1);
      if (p < NC) cidx[p] = e;
    }
  __syncthreads();
  const int ncand = min(snc, NC);
  for (int c = wid; c < ncand; c += 4) {
    const int e = cidx[c];
    const float* wrp = Wed + (size_t)e * D_DIM;
    double s = 0.0;
#pragma unroll
    for (int q = 0; q < 12; ++q)
      s = fma((double)xs[lane + (q << 6)], (double)wrp[lane + (q << 6)], s);
    const int rcnt = min(row_cnt[e], CAP);
    for (int n = lane; n < rcnt; n += 64) {
      const int jj = rowcols[(size_t)e * CAP + n];
      int lo = 0, hi = K_TOP - 1, found = -1;
      while (lo <= hi) {
        int mid = (lo + hi) >> 1;
        int a = aj[mid];
        if (a == jj) { found = mid; break; }
        if (a < jj) lo = mid + 1; else hi = mid - 1;
      }
      if (found >= 0)
        s = fma((double)av[found], (double)rowval[(size_t)e * CAP + n], s);
    }
#pragma unroll
    for (int off = 32; off; off >>= 1) s += __shfl_xor(s, off);
    if (lane == 0) cval[c] = s + (double)biasc[e] + (double)bed[e];
  }
  __syncthreads();
  for (int c = tid; c < ncand; c += 256) {
    const double v = cval[c];
    const int e = cidx[c];
    int r = 0;
    for (int p = 0; p < ncand; ++p) {
      double vp = cval[p];
      if (vp > v || (vp == v && cidx[p] < e)) ++r;
    }
    if (r < K_TOP) {
      dnv[(size_t)tok * K_TOP + r] = (float)v;
      dni[(size_t)tok * K_TOP + r] = e;
    }
  }
}

// ------------------------------------------------------------------
// Decode: recon[t,:] = sum_s v_s * WddT[f_s,:] + b_dec_down  (fp32)
// ------------------------------------------------------------------
__global__ __launch_bounds__(256) void decode_kernel(
    const float* __restrict__ dvals, const int* __restrict__ didx,
    const float* __restrict__ Wt, const float* __restrict__ bdd,
    float* __restrict__ out) {
  const int t = blockIdx.x, d = threadIdx.x;
  float a0 = bdd[d], a1 = bdd[d + 256], a2 = bdd[d + 512];
  for (int s = 0; s < K_TOP; ++s) {
    const float v = dvals[(size_t)t * K_TOP + s];
    const float* wr = Wt + (size_t)didx[(size_t)t * K_TOP + s] * D_DIM;
    a0 = fmaf(v, wr[d], a0);
    a1 = fmaf(v, wr[d + 256], a1);
    a2 = fmaf(v, wr[d + 512], a2);
  }
  float* o = out + (size_t)t * D_DIM;
  o[d] = a0; o[d + 256] = a1; o[d + 512] = a2;
}

// ------------------------------------------------------------------
extern "C" void kernel_launch(void* const* d_in, const int* in_sizes, int n_in,
                              void* d_out, int out_size, void* d_ws, size_t ws_size,
                              hipStream_t stream) {
  const float* x_up  = (const float*)d_in[0];
  const float* x_res = (const float*)d_in[1];
  const float* Weu   = (const float*)d_in[2];   // [F][D]
  const float* beu   = (const float*)d_in[3];   // [F]
  const float* bdu   = (const float*)d_in[4];   // [D]
  const float* Wdu   = (const float*)d_in[5];   // [D][F]
  const float* Wed   = (const float*)d_in[6];   // [F][D]
  const float* bed   = (const float*)d_in[7];   // [F]
  const float* bdd   = (const float*)d_in[8];   // [D]
  const float* Wdd   = (const float*)d_in[9];   // [D][F]
  const void*  mask  = d_in[10];
  float* out = (float*)d_out;

  char* w = (char*)d_ws;
  unsigned short* bufC    = (unsigned short*)(w);            // 100663296 B (bf16 C; also fp32 WduT/WddT staging)
  float*          bufF    = (float*)(w);                     // alias
  unsigned short* A_up    = (unsigned short*)(w + 100663296);  //  6291456
  unsigned short* A_dn    = (unsigned short*)(w + 106954752);  //  6291456
  unsigned short* Bu      = (unsigned short*)(w + 113246208);  // 18874368
  unsigned short* Bd      = (unsigned short*)(w + 132120576);  // 18874368
  float*          colval  = (float*)(w + 150994944);           // 12582912
  float*          rowval  = (float*)(w + 163577856);           // 12582912
  unsigned short* colrows = (unsigned short*)(w + 176160768);  //  6291456
  unsigned short* rowcols = (unsigned short*)(w + 182452224);  //  6291456
  unsigned char*  colrpos = (unsigned char*)(w + 188743680);   //  3145728
  int*            colcnt  = (int*)(w + 191889408);             //    49152
  int*            rowcnt  = (int*)(w + 191938560);             //    49152
  float*          biasc   = (float*)(w + 191987712);           //    49152
  int*            upj     = (int*)(w + 192036864);             //  1048576
  float*          upval   = (float*)(w + 193085440);           //  1048576
  float*          dnv     = (float*)(w + 194134016);           //  1048576
  int*            dni     = (int*)(w + 195182592);             //  1048576
  int*            mode    = (int*)(w + 196231168);             //      256
  if (ws_size < 196231424) return;

  hipMemsetAsync(colcnt, 0, 2 * F_DIM * sizeof(int), stream);  // colcnt+rowcnt
  detect_mask_kernel<<<1, 1024, 0, stream>>>(mask, mode);
  count_fill_kernel<<<8192, 256, 0, stream>>>(mask, mode, colcnt, rowcnt,
                                              colrows, colrpos, rowcols);
  // WduT staged in bufF (dead until up GEMM), consumed by csr_vals.
  transpose_kernel<<<dim3(F_DIM / 32, D_DIM / 32), dim3(32, 8), 0, stream>>>(Wdu, bufF);
  csr_vals_kernel<<<F_DIM, 256, 0, stream>>>(bufF, Wed, colrows, colrpos,
                                             colcnt, colval, rowval);
  bias_contrib_kernel<<<F_DIM / 4, 256, 0, stream>>>(bdu, Wed, biasc);
  // bf16 operand conversions
  conv_bf16_kernel<<<3072, 256, 0, stream>>>(x_up, bdu, A_up, (size_t)M_DIM * D_DIM);
  conv_bf16_kernel<<<3072, 256, 0, stream>>>(x_res, nullptr, A_dn, (size_t)M_DIM * D_DIM);
  conv_bf16_kernel<<<9216, 256, 0, stream>>>(Weu, nullptr, Bu, (size_t)F_DIM * D_DIM);
  conv_bf16_kernel<<<9216, 256, 0, stream>>>(Wed, nullptr, Bd, (size_t)F_DIM * D_DIM);
  // upstream: bf16 pre-acts (selection) -> fused topk + fp64 refine
  gemm_bf16<0, 1><<<3072, 256, 0, stream>>>(A_up, Bu, bufC, beu, beu);
  topk_up_kernel<<<M_DIM, 256, 0, stream>>>(bufC, x_up, bdu, Weu, beu, upj, upval);
  // downstream: bf16 base (initial + biases) -> fused scatter+topk+refine
  gemm_bf16<1, 0><<<3072, 256, 0, stream>>>(A_dn, Bd, bufC, biasc, bed);
  topk_dn_kernel<<<M_DIM, 256, 0, stream>>>(bufC, x_res, Wed, biasc, bed, upj,
                                            upval, colcnt, colrows, colval,
                                            rowcnt, rowcols, rowval, dnv, dni);
  // WddT into bufF (bufC now dead), then decode
  transpose_kernel<<<dim3(F_DIM / 32, D_DIM / 32), dim3(32, 8), 0, stream>>>(Wdd, bufF);
  decode_kernel<<<M_DIM, 256, 0, stream>>>(dnv, dni, bufF, bdd, out);
}